// Round 1
// baseline (32.380 us; speedup 1.0000x reference)
//
#include <hip/hip_runtime.h>
#include <math.h>

// Focal-weighted BCE-with-logits, mean-reduced.
// pred: [A,3] f32, targ: [A] int32 (jax default int even though ref says int64).
// col = targ==1 ? 0 : targ==3 ? 1 : 2 ; t = onehot(col)
// w   = t ? (1-x)^2 : x^2        (from pt = x*t + (1-x)*(1-t), w = (1-pt)^2)
// bce = max(x,0) - x*t + log1p(exp(-|x|))
// out = mean(w * bce)

__device__ __forceinline__ float elem_loss(float x, bool is_t) {
    float l = __logf(1.0f + __expf(-fabsf(x)));          // log1p(exp(-|x|)), fast-math ok (abs thr 3e-2)
    float bce = fmaxf(x, 0.0f) + l - (is_t ? x : 0.0f);
    float one_minus_pt = is_t ? (1.0f - x) : x;
    return one_minus_pt * one_minus_pt * bce;
}

__global__ __launch_bounds__(256) void focal_partial(
        const float* __restrict__ pred,
        const int*   __restrict__ targ,
        float*       __restrict__ partial,
        int n_anchors) {
    const int tid      = blockIdx.x * blockDim.x + threadIdx.x;
    const int nthreads = gridDim.x * blockDim.x;
    const int groups   = n_anchors >> 2;                 // 4 anchors per group

    const float4* __restrict__ p4 = (const float4*)pred;
    const int4*   __restrict__ t4 = (const int4*)targ;

    float acc = 0.0f;

    for (int g = tid; g < groups; g += nthreads) {
        float4 f0 = p4[g * 3 + 0];                       // 12 floats = 4 anchors x 3 classes
        float4 f1 = p4[g * 3 + 1];
        float4 f2 = p4[g * 3 + 2];
        int4   tg = t4[g];

        float f[12] = {f0.x, f0.y, f0.z, f0.w,
                       f1.x, f1.y, f1.z, f1.w,
                       f2.x, f2.y, f2.z, f2.w};
        int   tt[4] = {tg.x, tg.y, tg.z, tg.w};

        #pragma unroll
        for (int a = 0; a < 4; ++a) {
            int col = (tt[a] == 1) ? 0 : ((tt[a] == 3) ? 1 : 2);
            #pragma unroll
            for (int j = 0; j < 3; ++j) {
                acc += elem_loss(f[a * 3 + j], j == col);
            }
        }
    }

    // tail (n_anchors not multiple of 4) — defensive, A=8388608 has none
    const int rem_start = groups << 2;
    for (int i = rem_start + tid; i < n_anchors; i += nthreads) {
        int tv  = targ[i];
        int col = (tv == 1) ? 0 : ((tv == 3) ? 1 : 2);
        #pragma unroll
        for (int j = 0; j < 3; ++j)
            acc += elem_loss(pred[i * 3 + j], j == col);
    }

    // wave-64 shuffle reduce, then cross-wave via LDS
    #pragma unroll
    for (int off = 32; off; off >>= 1)
        acc += __shfl_down(acc, off, 64);

    __shared__ float sm[4];                              // 256 threads = 4 waves
    const int lane = threadIdx.x & 63;
    const int wave = threadIdx.x >> 6;
    if (lane == 0) sm[wave] = acc;
    __syncthreads();

    if (threadIdx.x == 0) {
        float s = sm[0] + sm[1] + sm[2] + sm[3];
        partial[blockIdx.x] = s;
    }
}

__global__ __launch_bounds__(256) void final_reduce(
        const float* __restrict__ partial, int nparts,
        float* __restrict__ out, float inv_total) {
    float acc = 0.0f;
    for (int i = threadIdx.x; i < nparts; i += blockDim.x)
        acc += partial[i];

    #pragma unroll
    for (int off = 32; off; off >>= 1)
        acc += __shfl_down(acc, off, 64);

    __shared__ float sm[4];
    const int lane = threadIdx.x & 63;
    const int wave = threadIdx.x >> 6;
    if (lane == 0) sm[wave] = acc;
    __syncthreads();

    if (threadIdx.x == 0)
        out[0] = (sm[0] + sm[1] + sm[2] + sm[3]) * inv_total;
}

extern "C" void kernel_launch(void* const* d_in, const int* in_sizes, int n_in,
                              void* d_out, int out_size, void* d_ws, size_t ws_size,
                              hipStream_t stream) {
    const float* pred = (const float*)d_in[0];
    const int*   targ = (const int*)d_in[1];
    float*       out  = (float*)d_out;
    float*       partial = (float*)d_ws;

    const int n_anchors = in_sizes[1];                   // in_sizes[0] = 3*A
    const int block = 256;
    const int grid  = 2048;                              // ~8 blocks/CU, grid-stride

    focal_partial<<<grid, block, 0, stream>>>(pred, targ, partial, n_anchors);

    const float inv_total = 1.0f / (3.0f * (float)n_anchors);
    final_reduce<<<1, block, 0, stream>>>(partial, grid, out, inv_total);
}